// Round 14
// baseline (111.069 us; speedup 1.0000x reference)
//
#include <hip/hip_runtime.h>
#include <hip/hip_fp8.h>
#include <math.h>

#define N 8192
#define D 512
#define TT 64              // 8192/128 tiles per side
#define NT 2080            // TT*(TT+1)/2
#define NEG_INF_SENT (-3.0e38f)
#define SCALE1 0x7F7F7F7F   // E8M0 = 127 -> 2^0 = 1.0 in all four bytes

typedef __attribute__((ext_vector_type(8))) int int8x;      // 32 fp8 in 8 VGPRs
typedef __attribute__((ext_vector_type(16))) float f32x16;  // 32x32 C/D frag

__device__ inline void lse_merge(float& m1, float& s1, float m2, float s2) {
    float M = fmaxf(m1, m2);
    s1 = s1 * __expf(m1 - M) + s2 * __expf(m2 - M);
    m1 = M;
}

// ---- fused cast(fp32->fp8 e4m3, fragment-swizzled layout) + row-sumsq --------
// xb layout: 32-row group g, K-chunk c (64 k), half h (16-B k-seg):
//   1-KB unit at ((g*16 + c*2 + h)<<10), interior offset (seg32*32 + row&31)*16
// = exactly the lane-order image the 32x32x64 MFMA operand wants
// (lane l: row l&31, k=(l>>5)*32 + h*16 + [0,16)).
__global__ __launch_bounds__(256) void cast_rowsq_kernel(const float* __restrict__ x,
                                                         unsigned char* __restrict__ xb,
                                                         float* __restrict__ sq) {
#pragma unroll
    for (int g4 = 0; g4 < 4; ++g4) {
        int row = blockIdx.x * 16 + g4 * 4 + (threadIdx.x >> 6);
        int lane = threadIdx.x & 63;
        const float4* xr = (const float4*)(x + (size_t)row * D);
        float4 a = xr[lane * 2], b = xr[lane * 2 + 1];
        float v[8] = {a.x, a.y, a.z, a.w, b.x, b.y, b.z, b.w};
        float s = 0.f;
        unsigned int byt[8];
#pragma unroll
        for (int e = 0; e < 8; ++e) {
            s += v[e] * v[e];
            __hip_fp8_e4m3 f8(v[e]);            // OCP e4m3fn
            byt[e] = (unsigned int)f8.__x;
        }
        uint2 pk;
        pk.x = byt[0] | (byt[1] << 8) | (byt[2] << 16) | (byt[3] << 24);
        pk.y = byt[4] | (byt[5] << 8) | (byt[6] << 16) | (byt[7] << 24);
        int g = row >> 5, rl = row & 31;
        int c = lane >> 3;                 // K-chunk (64)
        int l5 = (lane >> 2) & 1;          // 32-k segment within chunk
        int h = (lane >> 1) & 1;           // 16-B half within segment
        int bb = (lane & 1) << 3;          // byte within 16-B unit
        size_t addr = ((size_t)(g * 16 + c * 2 + h) << 10) + ((l5 * 32 + rl) << 4) + bb;
        *(uint2*)(xb + addr) = pk;
#pragma unroll
        for (int off = 32; off > 0; off >>= 1) s += __shfl_down(s, off, 64);
        if (lane == 0) sq[row] = s;
    }
}

// ---- LDS-free MX-fp8 MFMA pair kernel ----------------------------------------
// 128x128 tile, 4 waves, wave-tile 64x64 = 2x2 frags of 32x32x64 (acc 64 AGPR).
// Fragments load straight global->VGPR from the swizzled layout: each
// global_load_dwordx4 covers a contiguous 1KB unit at lane*16 (16 full cache
// lines). NO LDS, NO barriers in the K-loop: the compiler emits precise
// per-register vmcnt waits; load(c+1) issues after MFMA(c) -> 1-chunk-deep
// self-pipeline per wave; 3 blocks/CU (launch_bounds(256,3)) -> 12 independent
// waves per CU. C/D layout (m74/m101): col=lane&31,
// row=(reg&3)+8*(reg>>2)+4*(lane>>5).
__global__ __launch_bounds__(256, 3) void pair_mfma_kernel(const unsigned char* __restrict__ xb,
                                                           const float* __restrict__ sq,
                                                           float* __restrict__ bm,
                                                           float* __restrict__ bs) {
    const int p = blockIdx.x;
    const int b = (p & 7) * 260 + (p >> 3);          // XCD-contiguous runs (2080 = 8*260)
    int bi = 0;
    while ((bi + 1) * (2 * TT - bi) / 2 <= b) ++bi;
    const int bj = bi + (b - bi * (2 * TT - bi + 1) / 2);
    const int i0 = bi * 128, j0 = bj * 128;
    const int gA = i0 >> 5, gB = j0 >> 5;

    const int tid = threadIdx.x;
    const int lane = tid & 63;
    const int w = tid >> 6;          // 0..3
    const int wy = w >> 1, wx = w & 1;
    const int l31 = lane & 31;
    const int l5 = lane >> 5;

    // per-lane global offsets of this wave's 8 1-KB units (frag x half), chunk 0
    int aOff[2][2], bOff[2][2];
#pragma unroll
    for (int mi = 0; mi < 2; ++mi)
#pragma unroll
        for (int h = 0; h < 2; ++h) {
            aOff[mi][h] = (((gA + 2 * wy + mi) * 16 + h) << 10) + (lane << 4);
            bOff[mi][h] = (((gB + 2 * wx + mi) * 16 + h) << 10) + (lane << 4);
        }

    f32x16 acc[2][2];
#pragma unroll
    for (int mi = 0; mi < 2; ++mi)
#pragma unroll
        for (int ni = 0; ni < 2; ++ni)
#pragma unroll
            for (int r = 0; r < 16; ++r) acc[mi][ni][r] = 0.f;

    int8x af[2], bf[2];
    // load chunk c's 4 fragments directly into the MFMA operand registers
    auto load_chunk = [&](int c) {
        const int co = c << 11;     // c*2048
#pragma unroll
        for (int mi = 0; mi < 2; ++mi) {
            uint4 alo = *(const uint4*)(xb + aOff[mi][0] + co);
            uint4 ahi = *(const uint4*)(xb + aOff[mi][1] + co);
            uint4 blo = *(const uint4*)(xb + bOff[mi][0] + co);
            uint4 bhi = *(const uint4*)(xb + bOff[mi][1] + co);
            af[mi][0] = alo.x; af[mi][1] = alo.y; af[mi][2] = alo.z; af[mi][3] = alo.w;
            af[mi][4] = ahi.x; af[mi][5] = ahi.y; af[mi][6] = ahi.z; af[mi][7] = ahi.w;
            bf[mi][0] = blo.x; bf[mi][1] = blo.y; bf[mi][2] = blo.z; bf[mi][3] = blo.w;
            bf[mi][4] = bhi.x; bf[mi][5] = bhi.y; bf[mi][6] = bhi.z; bf[mi][7] = bhi.w;
        }
    };

    load_chunk(0);
#pragma unroll
    for (int c = 0; c < 8; ++c) {          // 8 K-chunks of 64
        int8x ca[2], cb[2];
        ca[0] = af[0]; ca[1] = af[1]; cb[0] = bf[0]; cb[1] = bf[1];
        if (c < 7) load_chunk(c + 1);      // issue next loads before consuming current
#pragma unroll
        for (int mi = 0; mi < 2; ++mi)
#pragma unroll
            for (int ni = 0; ni < 2; ++ni)
                acc[mi][ni] = __builtin_amdgcn_mfma_scale_f32_32x32x64_f8f6f4(
                    ca[mi], cb[ni], acc[mi][ni], 0, 0, 0, SCALE1, 0, SCALE1);
    }

    // ---- branch-free epilogue ------------------------------------------------
    const bool offdiag = (bi != bj);
    float sqj[2];
#pragma unroll
    for (int ni = 0; ni < 2; ++ni) sqj[ni] = sq[j0 + wx * 64 + ni * 32 + l31];

    float m = NEG_INF_SENT;
#pragma unroll
    for (int mi = 0; mi < 2; ++mi) {
#pragma unroll
        for (int r = 0; r < 16; ++r) {
            int row32 = (r & 3) + 8 * (r >> 2) + 4 * l5;
            int i = i0 + wy * 64 + mi * 32 + row32;
            float sqi = sq[i];
#pragma unroll
            for (int ni = 0; ni < 2; ++ni) {
                int j = j0 + wx * 64 + ni * 32 + l31;
                float d2 = fmaxf(sqi + sqj[ni] - 2.f * acc[mi][ni][r], 0.f);
                float tv = (offdiag || j > i) ? (-2.0f * d2) : NEG_INF_SENT;
                acc[mi][ni][r] = tv;
                m = fmaxf(m, tv);
            }
        }
    }
    float s = 0.f;
#pragma unroll
    for (int mi = 0; mi < 2; ++mi)
#pragma unroll
        for (int ni = 0; ni < 2; ++ni)
#pragma unroll
            for (int r = 0; r < 16; ++r)
                s += __expf(acc[mi][ni][r] - m);

#pragma unroll
    for (int off = 32; off > 0; off >>= 1) {
        float m2 = __shfl_down(m, off, 64);
        float s2 = __shfl_down(s, off, 64);
        lse_merge(m, s, m2, s2);
    }
    __shared__ float rm[4], rs[4];
    if (lane == 0) { rm[w] = m; rs[w] = s; }
    __syncthreads();
    if (tid == 0) {
#pragma unroll
        for (int v = 1; v < 4; ++v) lse_merge(rm[0], rs[0], rm[v], rs[v]);
        bm[p] = rm[0];
        bs[p] = rs[0];
    }
}

__global__ __launch_bounds__(256) void finalize_kernel(const float* __restrict__ bm,
                                                       const float* __restrict__ bs,
                                                       int nblocks,
                                                       float* __restrict__ out) {
    const int tid = threadIdx.x;
    float m = NEG_INF_SENT, s = 0.f;
    for (int b = tid; b < nblocks; b += 256) lse_merge(m, s, bm[b], bs[b]);
#pragma unroll
    for (int off = 32; off > 0; off >>= 1) {
        float m2 = __shfl_down(m, off, 64);
        float s2 = __shfl_down(s, off, 64);
        lse_merge(m, s, m2, s2);
    }
    __shared__ float rm[4], rs[4];
    if ((tid & 63) == 0) { rm[tid >> 6] = m; rs[tid >> 6] = s; }
    __syncthreads();
    if (tid == 0) {
#pragma unroll
        for (int v = 1; v < 4; ++v) lse_merge(rm[0], rs[0], rm[v], rs[v]);
        const float log_num_pairs = 17.3285362f;  // log(8192*8191/2)
        out[0] = rm[0] + logf(rs[0]) - log_num_pairs;
    }
}

extern "C" void kernel_launch(void* const* d_in, const int* in_sizes, int n_in,
                              void* d_out, int out_size, void* d_ws, size_t ws_size,
                              hipStream_t stream) {
    const float* x = (const float*)d_in[0];
    float* out = (float*)d_out;

    const size_t xb_bytes = (size_t)N * D;    // 4 MB fp8 (swizzled)
    unsigned char* xb = (unsigned char*)d_ws;
    float* sq = (float*)((char*)d_ws + xb_bytes);
    float* bm = sq + N;
    float* bs = bm + NT;

    cast_rowsq_kernel<<<N / 16, 256, 0, stream>>>(x, xb, sq);
    pair_mfma_kernel<<<NT, 256, 0, stream>>>(xb, sq, bm, bs);
    finalize_kernel<<<1, 256, 0, stream>>>(bm, bs, NT, out);
}

// Round 15
// 103.103 us; speedup vs baseline: 1.0773x; 1.0773x over previous
//
#include <hip/hip_runtime.h>
#include <hip/hip_fp8.h>
#include <math.h>

#define N 8192
#define D 512
#define TT 64              // 8192/128 tiles per side
#define NT 2080            // TT*(TT+1)/2
#define NEG_INF_SENT (-3.0e38f)
#define SCALE1 0x7F7F7F7F   // E8M0 = 127 -> 2^0 = 1.0 in all four bytes

typedef __attribute__((ext_vector_type(8))) int int8x;      // 32 fp8 in 8 VGPRs
typedef __attribute__((ext_vector_type(16))) float f32x16;  // 32x32 C/D frag

__device__ inline void lse_merge(float& m1, float& s1, float m2, float s2) {
    float M = fmaxf(m1, m2);
    s1 = s1 * __expf(m1 - M) + s2 * __expf(m2 - M);
    m1 = M;
}

// ---- fused cast(fp32->fp8 e4m3, fragment-swizzled layout) + row-sumsq --------
// xb layout: 32-row group g, K-chunk c (64 k), half h (16-B k-seg):
//   1-KB unit at ((g*16 + c*2 + h)<<10), interior offset (seg32*32 + row&31)*16
// = exactly the lane-order image the 32x32x64 MFMA operand wants
// (lane l: row l&31, k=(l>>5)*32 + h*16 + [0,16)).
__global__ __launch_bounds__(256) void cast_rowsq_kernel(const float* __restrict__ x,
                                                         unsigned char* __restrict__ xb,
                                                         float* __restrict__ sq) {
#pragma unroll
    for (int g4 = 0; g4 < 4; ++g4) {
        int row = blockIdx.x * 16 + g4 * 4 + (threadIdx.x >> 6);
        int lane = threadIdx.x & 63;
        const float4* xr = (const float4*)(x + (size_t)row * D);
        float4 a = xr[lane * 2], b = xr[lane * 2 + 1];
        float v[8] = {a.x, a.y, a.z, a.w, b.x, b.y, b.z, b.w};
        float s = 0.f;
        unsigned int byt[8];
#pragma unroll
        for (int e = 0; e < 8; ++e) {
            s += v[e] * v[e];
            __hip_fp8_e4m3 f8(v[e]);            // OCP e4m3fn
            byt[e] = (unsigned int)f8.__x;
        }
        uint2 pk;
        pk.x = byt[0] | (byt[1] << 8) | (byt[2] << 16) | (byt[3] << 24);
        pk.y = byt[4] | (byt[5] << 8) | (byt[6] << 16) | (byt[7] << 24);
        int g = row >> 5, rl = row & 31;
        int c = lane >> 3;                 // K-chunk (64)
        int l5 = (lane >> 2) & 1;          // 32-k segment within chunk
        int h = (lane >> 1) & 1;           // 16-B half within segment
        int bb = (lane & 1) << 3;          // byte within 16-B unit
        size_t addr = ((size_t)(g * 16 + c * 2 + h) << 10) + ((l5 * 32 + rl) << 4) + bb;
        *(uint2*)(xb + addr) = pk;
#pragma unroll
        for (int off = 32; off > 0; off >>= 1) s += __shfl_down(s, off, 64);
        if (lane == 0) sq[row] = s;
    }
}

// ---- LDS-free MX-fp8 MFMA pair kernel (register ping-pong, no copies) --------
// 128x128 tile, 4 waves, wave-tile 64x64 = 2x2 frags of 32x32x64 (acc 64 AGPR).
// Fragments load straight global->VGPR from the swizzled layout (dense 1KB
// units at lane*16 = 16 full cache lines). No LDS, no barriers in the K-loop.
// Operand double-buffer af[2]/bf[2] parity-indexed, K-loop fully unrolled ->
// zero v_mov copies; ~150 live regs under launch_bounds(256,2)'s 256 cap
// (r14's copies+cap-170 spilled 45.8 MB scratch -> that's the fix here).
// C/D layout (m74/m101): col=lane&31, row=(reg&3)+8*(reg>>2)+4*(lane>>5).
__global__ __launch_bounds__(256, 2) void pair_mfma_kernel(const unsigned char* __restrict__ xb,
                                                           const float* __restrict__ sq,
                                                           float* __restrict__ bm,
                                                           float* __restrict__ bs) {
    const int p = blockIdx.x;
    const int b = (p & 7) * 260 + (p >> 3);          // XCD-contiguous runs (2080 = 8*260)
    int bi = 0;
    while ((bi + 1) * (2 * TT - bi) / 2 <= b) ++bi;
    const int bj = bi + (b - bi * (2 * TT - bi + 1) / 2);
    const int i0 = bi * 128, j0 = bj * 128;
    const int gA = i0 >> 5, gB = j0 >> 5;

    const int tid = threadIdx.x;
    const int lane = tid & 63;
    const int w = tid >> 6;          // 0..3
    const int wy = w >> 1, wx = w & 1;
    const int l31 = lane & 31;
    const int l5 = lane >> 5;

    // per-lane global offsets of this wave's 8 1-KB units (frag x half), chunk 0
    int aOff[2][2], bOff[2][2];
#pragma unroll
    for (int mi = 0; mi < 2; ++mi)
#pragma unroll
        for (int h = 0; h < 2; ++h) {
            aOff[mi][h] = (((gA + 2 * wy + mi) * 16 + h) << 10) + (lane << 4);
            bOff[mi][h] = (((gB + 2 * wx + mi) * 16 + h) << 10) + (lane << 4);
        }

    f32x16 acc[2][2];
#pragma unroll
    for (int mi = 0; mi < 2; ++mi)
#pragma unroll
        for (int ni = 0; ni < 2; ++ni)
#pragma unroll
            for (int r = 0; r < 16; ++r) acc[mi][ni][r] = 0.f;

    int8x af[2][2], bf[2][2];    // [buf][frag]
    // load chunk c's 4 fragments into operand buffer `buf`
    auto load_chunk = [&](int c, int buf) {
        const int co = c << 11;     // c*2048
#pragma unroll
        for (int mi = 0; mi < 2; ++mi) {
            uint4 alo = *(const uint4*)(xb + aOff[mi][0] + co);
            uint4 ahi = *(const uint4*)(xb + aOff[mi][1] + co);
            uint4 blo = *(const uint4*)(xb + bOff[mi][0] + co);
            uint4 bhi = *(const uint4*)(xb + bOff[mi][1] + co);
            af[buf][mi][0] = alo.x; af[buf][mi][1] = alo.y;
            af[buf][mi][2] = alo.z; af[buf][mi][3] = alo.w;
            af[buf][mi][4] = ahi.x; af[buf][mi][5] = ahi.y;
            af[buf][mi][6] = ahi.z; af[buf][mi][7] = ahi.w;
            bf[buf][mi][0] = blo.x; bf[buf][mi][1] = blo.y;
            bf[buf][mi][2] = blo.z; bf[buf][mi][3] = blo.w;
            bf[buf][mi][4] = bhi.x; bf[buf][mi][5] = bhi.y;
            bf[buf][mi][6] = bhi.z; bf[buf][mi][7] = bhi.w;
        }
    };

    load_chunk(0, 0);
#pragma unroll
    for (int c = 0; c < 8; ++c) {          // 8 K-chunks of 64, ping-pong buffers
        const int cur = c & 1;
        if (c < 7) load_chunk(c + 1, cur ^ 1);   // fills the other buffer; no WAR
#pragma unroll
        for (int mi = 0; mi < 2; ++mi)
#pragma unroll
            for (int ni = 0; ni < 2; ++ni)
                acc[mi][ni] = __builtin_amdgcn_mfma_scale_f32_32x32x64_f8f6f4(
                    af[cur][mi], bf[cur][ni], acc[mi][ni], 0, 0, 0, SCALE1, 0, SCALE1);
    }

    // ---- branch-free epilogue ------------------------------------------------
    const bool offdiag = (bi != bj);
    float sqj[2];
#pragma unroll
    for (int ni = 0; ni < 2; ++ni) sqj[ni] = sq[j0 + wx * 64 + ni * 32 + l31];

    float m = NEG_INF_SENT;
#pragma unroll
    for (int mi = 0; mi < 2; ++mi) {
#pragma unroll
        for (int r = 0; r < 16; ++r) {
            int row32 = (r & 3) + 8 * (r >> 2) + 4 * l5;
            int i = i0 + wy * 64 + mi * 32 + row32;
            float sqi = sq[i];
#pragma unroll
            for (int ni = 0; ni < 2; ++ni) {
                int j = j0 + wx * 64 + ni * 32 + l31;
                float d2 = fmaxf(sqi + sqj[ni] - 2.f * acc[mi][ni][r], 0.f);
                float tv = (offdiag || j > i) ? (-2.0f * d2) : NEG_INF_SENT;
                acc[mi][ni][r] = tv;
                m = fmaxf(m, tv);
            }
        }
    }
    float s = 0.f;
#pragma unroll
    for (int mi = 0; mi < 2; ++mi)
#pragma unroll
        for (int ni = 0; ni < 2; ++ni)
#pragma unroll
            for (int r = 0; r < 16; ++r)
                s += __expf(acc[mi][ni][r] - m);

#pragma unroll
    for (int off = 32; off > 0; off >>= 1) {
        float m2 = __shfl_down(m, off, 64);
        float s2 = __shfl_down(s, off, 64);
        lse_merge(m, s, m2, s2);
    }
    __shared__ float rm[4], rs[4];
    if (lane == 0) { rm[w] = m; rs[w] = s; }
    __syncthreads();
    if (tid == 0) {
#pragma unroll
        for (int v = 1; v < 4; ++v) lse_merge(rm[0], rs[0], rm[v], rs[v]);
        bm[p] = rm[0];
        bs[p] = rs[0];
    }
}

__global__ __launch_bounds__(256) void finalize_kernel(const float* __restrict__ bm,
                                                       const float* __restrict__ bs,
                                                       int nblocks,
                                                       float* __restrict__ out) {
    const int tid = threadIdx.x;
    float m = NEG_INF_SENT, s = 0.f;
    for (int b = tid; b < nblocks; b += 256) lse_merge(m, s, bm[b], bs[b]);
#pragma unroll
    for (int off = 32; off > 0; off >>= 1) {
        float m2 = __shfl_down(m, off, 64);
        float s2 = __shfl_down(s, off, 64);
        lse_merge(m, s, m2, s2);
    }
    __shared__ float rm[4], rs[4];
    if ((tid & 63) == 0) { rm[tid >> 6] = m; rs[tid >> 6] = s; }
    __syncthreads();
    if (tid == 0) {
#pragma unroll
        for (int v = 1; v < 4; ++v) lse_merge(rm[0], rs[0], rm[v], rs[v]);
        const float log_num_pairs = 17.3285362f;  // log(8192*8191/2)
        out[0] = rm[0] + logf(rs[0]) - log_num_pairs;
    }
}

extern "C" void kernel_launch(void* const* d_in, const int* in_sizes, int n_in,
                              void* d_out, int out_size, void* d_ws, size_t ws_size,
                              hipStream_t stream) {
    const float* x = (const float*)d_in[0];
    float* out = (float*)d_out;

    const size_t xb_bytes = (size_t)N * D;    // 4 MB fp8 (swizzled)
    unsigned char* xb = (unsigned char*)d_ws;
    float* sq = (float*)((char*)d_ws + xb_bytes);
    float* bm = sq + N;
    float* bs = bm + NT;

    cast_rowsq_kernel<<<N / 16, 256, 0, stream>>>(x, xb, sq);
    pair_mfma_kernel<<<NT, 256, 0, stream>>>(xb, sq, bm, bs);
    finalize_kernel<<<1, 256, 0, stream>>>(bm, bs, NT, out);
}

// Round 16
// 90.146 us; speedup vs baseline: 1.2321x; 1.1437x over previous
//
#include <hip/hip_runtime.h>
#include <math.h>

#define N 8192
#define D 512
#define TT 64              // 8192/128 tiles per side
#define NT 2080            // TT*(TT+1)/2
#define NEG_INF_SENT (-3.0e38f)
#define SCALE1 0x7F7F7F7F   // E8M0 = 127 -> 2^0 = 1.0 in all four bytes
#define FMT_FP4 4           // cbsz/blgp format code for fp4 (e2m1)

typedef __attribute__((ext_vector_type(8))) int int8x;      // operand regs (fp4 uses low 4)
typedef __attribute__((ext_vector_type(16))) float f32x16;  // 32x32 C/D frag

__device__ inline void lse_merge(float& m1, float& s1, float m2, float s2) {
    float M = fmaxf(m1, m2);
    s1 = s1 * __expf(m1 - M) + s2 * __expf(m2 - M);
    m1 = M;
}

__device__ inline unsigned fp4_nib(float v) {
    // e2m1 nearest: values 0,.5,1,1.5,2,3,4,6 (sign bit 3)
    unsigned s = (__float_as_uint(v) >> 28) & 8u;
    float av = fabsf(v);
    unsigned c;
    if (av < 1.25f)      c = (av < 0.25f) ? 0u : (av < 0.75f) ? 1u : 2u;
    else if (av < 2.5f)  c = (av < 1.75f) ? 3u : 4u;
    else                 c = (av < 3.5f) ? 5u : (av < 5.0f) ? 6u : 7u;
    return s | c;
}

// ---- fused cast(fp32->fp4 e2m1, fragment-swizzled layout) + row-sumsq --------
// xb layout: 32-row group g (0..255), K-chunk c (64 k, 0..7): one 1-KB unit at
// ((g*8+c)<<10); interior offset = ((kseg32*32 + row&31)<<4) + (k&31)/2  ==
// lane*16 for the MFMA operand read (lane l: row l&31, k=(l>>5)*32+[0,32)).
// Nibble order: k ascending, low nibble first.
__global__ __launch_bounds__(256) void cast_rowsq_kernel(const float* __restrict__ x,
                                                         unsigned char* __restrict__ xb,
                                                         float* __restrict__ sq) {
#pragma unroll
    for (int g4 = 0; g4 < 4; ++g4) {
        int row = blockIdx.x * 16 + g4 * 4 + (threadIdx.x >> 6);
        int lane = threadIdx.x & 63;
        const float4* xr = (const float4*)(x + (size_t)row * D);
        float4 a = xr[lane * 2], b = xr[lane * 2 + 1];
        float v[8] = {a.x, a.y, a.z, a.w, b.x, b.y, b.z, b.w};
        float s = 0.f;
        unsigned pk = 0;
#pragma unroll
        for (int e = 0; e < 8; ++e) {
            s += v[e] * v[e];
            pk |= fp4_nib(v[e]) << (4 * e);
        }
        int g = row >> 5, rl = row & 31;
        int k0 = lane * 8;
        int c = k0 >> 6;                   // K-chunk
        int seg = (k0 >> 5) & 1;           // 32-k segment
        int bb = (k0 & 31) >> 1;           // byte within 16-B row-seg: 0,4,8,12
        size_t addr = ((size_t)(g * 8 + c) << 10) + ((seg * 32 + rl) << 4) + bb;
        *(unsigned*)(xb + addr) = pk;
#pragma unroll
        for (int off = 32; off > 0; off >>= 1) s += __shfl_down(s, off, 64);
        if (lane == 0) sq[row] = s;
    }
}

// ---- LDS-free MX-fp4 MFMA pair kernel ----------------------------------------
// 128x128 tile, 4 waves, wave-tile 64x64 = 2x2 frags of 32x32x64 (acc 64 AGPR).
// fp4 halves staged bytes vs fp8 (r15): 4 dense 1-KB fragment loads per chunk
// (one dwordx4/lane each), no LDS, no K-loop barriers, register ping-pong.
// mfma_scale..._f8f6f4 with cbsz=blgp=4 (fp4), unit E8M0 scales.
// C/D layout (m74/m101, shape-determined): col=lane&31,
// row=(reg&3)+8*(reg>>2)+4*(lane>>5).
__global__ __launch_bounds__(256, 2) void pair_mfma_kernel(const unsigned char* __restrict__ xb,
                                                           const float* __restrict__ sq,
                                                           float* __restrict__ bm,
                                                           float* __restrict__ bs) {
    const int p = blockIdx.x;
    const int b = (p & 7) * 260 + (p >> 3);          // XCD-contiguous runs (2080 = 8*260)
    int bi = 0;
    while ((bi + 1) * (2 * TT - bi) / 2 <= b) ++bi;
    const int bj = bi + (b - bi * (2 * TT - bi + 1) / 2);
    const int i0 = bi * 128, j0 = bj * 128;
    const int gA = i0 >> 5, gB = j0 >> 5;

    const int tid = threadIdx.x;
    const int lane = tid & 63;
    const int w = tid >> 6;          // 0..3
    const int wy = w >> 1, wx = w & 1;
    const int l31 = lane & 31;
    const int l5 = lane >> 5;

    // per-lane base offsets of this wave's 4 fragment units (chunk 0)
    int aOff[2], bOff[2];
#pragma unroll
    for (int mi = 0; mi < 2; ++mi) {
        aOff[mi] = (((gA + 2 * wy + mi) * 8) << 10) + (lane << 4);
        bOff[mi] = (((gB + 2 * wx + mi) * 8) << 10) + (lane << 4);
    }

    f32x16 acc[2][2];
#pragma unroll
    for (int mi = 0; mi < 2; ++mi)
#pragma unroll
        for (int ni = 0; ni < 2; ++ni)
#pragma unroll
            for (int r = 0; r < 16; ++r) acc[mi][ni][r] = 0.f;

    int8x af[2][2], bf[2][2];    // [buf][frag]; fp4 uses regs 0..3, 4..7 stay 0
#pragma unroll
    for (int buf = 0; buf < 2; ++buf)
#pragma unroll
        for (int mi = 0; mi < 2; ++mi)
#pragma unroll
            for (int r = 0; r < 8; ++r) { af[buf][mi][r] = 0; bf[buf][mi][r] = 0; }

    auto load_chunk = [&](int c, int buf) {
        const int co = c << 10;     // c*1024
#pragma unroll
        for (int mi = 0; mi < 2; ++mi) {
            uint4 av = *(const uint4*)(xb + aOff[mi] + co);
            uint4 bv = *(const uint4*)(xb + bOff[mi] + co);
            af[buf][mi][0] = av.x; af[buf][mi][1] = av.y;
            af[buf][mi][2] = av.z; af[buf][mi][3] = av.w;
            bf[buf][mi][0] = bv.x; bf[buf][mi][1] = bv.y;
            bf[buf][mi][2] = bv.z; bf[buf][mi][3] = bv.w;
        }
    };

    load_chunk(0, 0);
#pragma unroll
    for (int c = 0; c < 8; ++c) {          // 8 K-chunks of 64, ping-pong buffers
        const int cur = c & 1;
        if (c < 7) load_chunk(c + 1, cur ^ 1);
#pragma unroll
        for (int mi = 0; mi < 2; ++mi)
#pragma unroll
            for (int ni = 0; ni < 2; ++ni)
                acc[mi][ni] = __builtin_amdgcn_mfma_scale_f32_32x32x64_f8f6f4(
                    af[cur][mi], bf[cur][ni], acc[mi][ni],
                    FMT_FP4, FMT_FP4, 0, SCALE1, 0, SCALE1);
    }

    // ---- branch-free epilogue ------------------------------------------------
    const bool offdiag = (bi != bj);
    float sqj[2];
#pragma unroll
    for (int ni = 0; ni < 2; ++ni) sqj[ni] = sq[j0 + wx * 64 + ni * 32 + l31];

    float m = NEG_INF_SENT;
#pragma unroll
    for (int mi = 0; mi < 2; ++mi) {
#pragma unroll
        for (int r = 0; r < 16; ++r) {
            int row32 = (r & 3) + 8 * (r >> 2) + 4 * l5;
            int i = i0 + wy * 64 + mi * 32 + row32;
            float sqi = sq[i];
#pragma unroll
            for (int ni = 0; ni < 2; ++ni) {
                int j = j0 + wx * 64 + ni * 32 + l31;
                float d2 = fmaxf(sqi + sqj[ni] - 2.f * acc[mi][ni][r], 0.f);
                float tv = (offdiag || j > i) ? (-2.0f * d2) : NEG_INF_SENT;
                acc[mi][ni][r] = tv;
                m = fmaxf(m, tv);
            }
        }
    }
    float s = 0.f;
#pragma unroll
    for (int mi = 0; mi < 2; ++mi)
#pragma unroll
        for (int ni = 0; ni < 2; ++ni)
#pragma unroll
            for (int r = 0; r < 16; ++r)
                s += __expf(acc[mi][ni][r] - m);

#pragma unroll
    for (int off = 32; off > 0; off >>= 1) {
        float m2 = __shfl_down(m, off, 64);
        float s2 = __shfl_down(s, off, 64);
        lse_merge(m, s, m2, s2);
    }
    __shared__ float rm[4], rs[4];
    if (lane == 0) { rm[w] = m; rs[w] = s; }
    __syncthreads();
    if (tid == 0) {
#pragma unroll
        for (int v = 1; v < 4; ++v) lse_merge(rm[0], rs[0], rm[v], rs[v]);
        bm[p] = rm[0];
        bs[p] = rs[0];
    }
}

__global__ __launch_bounds__(256) void finalize_kernel(const float* __restrict__ bm,
                                                       const float* __restrict__ bs,
                                                       int nblocks,
                                                       float* __restrict__ out) {
    const int tid = threadIdx.x;
    float m = NEG_INF_SENT, s = 0.f;
    for (int b = tid; b < nblocks; b += 256) lse_merge(m, s, bm[b], bs[b]);
#pragma unroll
    for (int off = 32; off > 0; off >>= 1) {
        float m2 = __shfl_down(m, off, 64);
        float s2 = __shfl_down(s, off, 64);
        lse_merge(m, s, m2, s2);
    }
    __shared__ float rm[4], rs[4];
    if ((tid & 63) == 0) { rm[tid >> 6] = m; rs[tid >> 6] = s; }
    __syncthreads();
    if (tid == 0) {
#pragma unroll
        for (int v = 1; v < 4; ++v) lse_merge(rm[0], rs[0], rm[v], rs[v]);
        const float log_num_pairs = 17.3285362f;  // log(8192*8191/2)
        out[0] = rm[0] + logf(rs[0]) - log_num_pairs;
    }
}

extern "C" void kernel_launch(void* const* d_in, const int* in_sizes, int n_in,
                              void* d_out, int out_size, void* d_ws, size_t ws_size,
                              hipStream_t stream) {
    const float* x = (const float*)d_in[0];
    float* out = (float*)d_out;

    const size_t xb_bytes = (size_t)N * D / 2;   // 2 MB fp4 (swizzled)
    unsigned char* xb = (unsigned char*)d_ws;
    float* sq = (float*)((char*)d_ws + xb_bytes);
    float* bm = sq + N;
    float* bs = bm + NT;

    cast_rowsq_kernel<<<N / 16, 256, 0, stream>>>(x, xb, sq);
    pair_mfma_kernel<<<NT, 256, 0, stream>>>(xb, sq, bm, bs);
    finalize_kernel<<<1, 256, 0, stream>>>(bm, bs, NT, out);
}